// Round 1
// baseline (185.617 us; speedup 1.0000x reference)
//
#include <hip/hip_runtime.h>
#include <math.h>

// ConvCaps + EM routing, MI355X (gfx950).
// Shapes: caps (8,24,24,32,17) f32, trans (3,3,32,32,4,4) f32, out (8,11,11,32,17) f32.
// One 256-thread block per (b, n=oy*11+ox). Patch staged in LDS; votes recomputed
// per sweep (T slices L2-resident); mu/sigma fused via E[V^2]-mu^2 (exact rewrite).

namespace {

constexpr int NH   = 11;    // output spatial dim
constexpr int NI   = 288;   // 3*3*32 input capsules per position
constexpr int NO   = 32;    // output capsules
constexpr float LAM_   = 0.01f;
constexpr float EPS_   = 1e-8f;
constexpr float LOG2PI = 1.8378770664093453f;

__device__ __forceinline__ void mat4_mul(const float* P, const float* T, float* V) {
#pragma unroll
    for (int p = 0; p < 4; ++p) {
#pragma unroll
        for (int r = 0; r < 4; ++r) {
            float s = P[p * 4 + 0] * T[0 * 4 + r];
            s = fmaf(P[p * 4 + 1], T[1 * 4 + r], s);
            s = fmaf(P[p * 4 + 2], T[2 * 4 + r], s);
            s = fmaf(P[p * 4 + 3], T[3 * 4 + r], s);
            V[p * 4 + r] = s;
        }
    }
}

__global__ __launch_bounds__(256, 2)
void convcaps_em_kernel(const float* __restrict__ caps,
                        const float* __restrict__ Tm,
                        const float* __restrict__ bu_p,
                        const float* __restrict__ ba_p,
                        float* __restrict__ out)
{
    // LDS total: 18432+1152+38016+16896+2176+2176+128+128+1024 = 80128 B -> 2 blocks/CU
    __shared__ float pose_s[NI][16];     // poses, 16 floats per input capsule
    __shared__ float act_s[NI];          // activations
    __shared__ float Ra_s[NI][33];       // R*a, stride 33: bank=(i+o)&31 -> conflict-free
    __shared__ float red_s[4][NO][33];   // per-wave partials: m1[16], m2[16], sumR
    __shared__ float mu_s[NO][17];       // stride 17 (gcd(17,32)=1) -> conflict-free bcast
    __shared__ float i2s_s[NO][17];      // 1/(2*sigma^2)
    __shared__ float C_s[NO];            // lnp per-o constant: log(a+eps) - (L + 8*log2pi)
    __shared__ float sumR_s[NO];
    __shared__ float csum_s[NO][8];      // partial sums of 0.5*log(sigma^2) over p

    const int n  = blockIdx.x;           // 0..120
    const int b  = blockIdx.y;           // 0..7
    const int oy = n / NH;
    const int ox = n - oy * NH;
    const int t  = (int)threadIdx.x;
    const int o  = t & 31;               // output capsule
    const int ig = t >> 5;               // i-group 0..7
    const int wv = t >> 6;               // wave 0..3
    const int ln = t & 63;               // lane

    // ---- stage patch: 9 spatial cells x (32 caps * 17 floats) ----
    for (int idx = t; idx < 9 * 544; idx += 256) {
        int cell = idx / 544;
        int j    = idx - cell * 544;     // j = ic*17 + c
        int kx   = cell / 3;
        int ky   = cell - kx * 3;
        size_t src = ((((size_t)b * 24 + (2 * oy + kx)) * 24 + (2 * ox + ky)) * 32) * 17 + j;
        float v = caps[src];
        int ic = j / 17;
        int c  = j - ic * 17;
        int i  = cell * 32 + ic;
        if (c == 16) act_s[i] = v;
        else         pose_s[i][c] = v;
    }
    __syncthreads();

    const float beta_u = bu_p[0];
    const float beta_a = ba_p[0];
    const size_t obase = ((((size_t)b * NH + oy) * NH + ox) * NO + o) * 17;

    for (int it = 0; it < 3; ++it) {
        // ======== moment sweep: m1 = sum Ra*V, m2 = sum Ra*V^2, sR = sum Ra ========
        float m1[16], m2[16];
#pragma unroll
        for (int k = 0; k < 16; ++k) { m1[k] = 0.f; m2[k] = 0.f; }
        float sR = 0.f;

        for (int ii = 0; ii < NI / 8; ++ii) {
            const int i = ig + ii * 8;   // within a wave the two ig's differ by 1 -> LDS banks split
            float ra = (it == 0) ? act_s[i] * (1.0f / 32.0f) : Ra_s[i][o];

            float P[16], T[16], V[16];
            const float4* pp = reinterpret_cast<const float4*>(&pose_s[i][0]);
            float4 a0 = pp[0], a1 = pp[1], a2 = pp[2], a3 = pp[3];
            P[0]=a0.x; P[1]=a0.y; P[2]=a0.z; P[3]=a0.w;
            P[4]=a1.x; P[5]=a1.y; P[6]=a1.z; P[7]=a1.w;
            P[8]=a2.x; P[9]=a2.y; P[10]=a2.z; P[11]=a2.w;
            P[12]=a3.x; P[13]=a3.y; P[14]=a3.z; P[15]=a3.w;
            const float4* tp = reinterpret_cast<const float4*>(Tm + ((size_t)i * 32 + o) * 16);
            float4 b0 = tp[0], b1 = tp[1], b2 = tp[2], b3 = tp[3];
            T[0]=b0.x; T[1]=b0.y; T[2]=b0.z; T[3]=b0.w;
            T[4]=b1.x; T[5]=b1.y; T[6]=b1.z; T[7]=b1.w;
            T[8]=b2.x; T[9]=b2.y; T[10]=b2.z; T[11]=b2.w;
            T[12]=b3.x; T[13]=b3.y; T[14]=b3.z; T[15]=b3.w;

            mat4_mul(P, T, V);
#pragma unroll
            for (int k = 0; k < 16; ++k) {
                m1[k] = fmaf(ra, V[k], m1[k]);
                m2[k] = fmaf(ra * V[k], V[k], m2[k]);
            }
            sR += ra;
        }

        // intra-wave: combine the two ig's (lane ^ 32)
#pragma unroll
        for (int k = 0; k < 16; ++k) {
            m1[k] += __shfl_xor(m1[k], 32);
            m2[k] += __shfl_xor(m2[k], 32);
        }
        sR += __shfl_xor(sR, 32);
        if (ln < 32) {
#pragma unroll
            for (int k = 0; k < 16; ++k) {
                red_s[wv][o][k]      = m1[k];
                red_s[wv][o][16 + k] = m2[k];
            }
            red_s[wv][o][32] = sR;
        }
        __syncthreads();

        // cross-wave reduce; thread (o, pg) finalizes p0=pg and p1=pg+8
        const int pg = ig;
        const int p0 = pg, p1 = pg + 8;
        float M10 = red_s[0][o][p0] + red_s[1][o][p0] + red_s[2][o][p0] + red_s[3][o][p0];
        float M20 = red_s[0][o][16+p0] + red_s[1][o][16+p0] + red_s[2][o][16+p0] + red_s[3][o][16+p0];
        float M11 = red_s[0][o][p1] + red_s[1][o][p1] + red_s[2][o][p1] + red_s[3][o][p1];
        float M21 = red_s[0][o][16+p1] + red_s[1][o][16+p1] + red_s[2][o][16+p1] + red_s[3][o][16+p1];
        if (pg == 0) {
            float S = red_s[0][o][32] + red_s[1][o][32] + red_s[2][o][32] + red_s[3][o][32];
            sumR_s[o] = S + EPS_;
        }
        __syncthreads();

        const float sumR = sumR_s[o];
        const float Sraw = sumR - EPS_;
        float mu0 = M10 / sumR;
        float sg0 = (M20 - 2.f * mu0 * M10 + mu0 * mu0 * Sraw) / sumR + EPS_;
        float mu1 = M11 / sumR;
        float sg1 = (M21 - 2.f * mu1 * M11 + mu1 * mu1 * Sraw) / sumR + EPS_;
        mu_s[o][p0]  = mu0;  mu_s[o][p1]  = mu1;
        i2s_s[o][p0] = 0.5f / sg0;  i2s_s[o][p1] = 0.5f / sg1;
        csum_s[o][pg] = 0.5f * (__logf(sg0) + __logf(sg1));
        __syncthreads();

        if (it == 2) {
            // ======== final outputs ========
            if (pg == 0) {
                float L = csum_s[o][0] + csum_s[o][1] + csum_s[o][2] + csum_s[o][3]
                        + csum_s[o][4] + csum_s[o][5] + csum_s[o][6] + csum_s[o][7];
                float cost = sumR * (16.f * beta_u + L);
                float a = 1.f / (1.f + __expf(-(LAM_ * (beta_a - cost))));
                out[obase + 16] = a;
            }
            out[obase + p0] = mu0;
            out[obase + p1] = mu1;
        } else {
            if (pg == 0) {
                float L = csum_s[o][0] + csum_s[o][1] + csum_s[o][2] + csum_s[o][3]
                        + csum_s[o][4] + csum_s[o][5] + csum_s[o][6] + csum_s[o][7];
                float cost = sumR * (16.f * beta_u + L);
                float a = 1.f / (1.f + __expf(-(LAM_ * (beta_a - cost))));
                C_s[o] = __logf(a + EPS_) - (L + 8.f * LOG2PI);
            }
            __syncthreads();

            // ======== ln_p sweep: Ra_s[i][o] <- C[o] - sum_p (V-mu)^2 * i2s ========
            const float Cc = C_s[o];
            float MU[16], IS[16];
#pragma unroll
            for (int k = 0; k < 16; ++k) { MU[k] = mu_s[o][k]; IS[k] = i2s_s[o][k]; }

            for (int ii = 0; ii < NI / 8; ++ii) {
                const int i = ig + ii * 8;
                float P[16], T[16], V[16];
                const float4* pp = reinterpret_cast<const float4*>(&pose_s[i][0]);
                float4 a0 = pp[0], a1 = pp[1], a2 = pp[2], a3 = pp[3];
                P[0]=a0.x; P[1]=a0.y; P[2]=a0.z; P[3]=a0.w;
                P[4]=a1.x; P[5]=a1.y; P[6]=a1.z; P[7]=a1.w;
                P[8]=a2.x; P[9]=a2.y; P[10]=a2.z; P[11]=a2.w;
                P[12]=a3.x; P[13]=a3.y; P[14]=a3.z; P[15]=a3.w;
                const float4* tp = reinterpret_cast<const float4*>(Tm + ((size_t)i * 32 + o) * 16);
                float4 b0 = tp[0], b1 = tp[1], b2 = tp[2], b3 = tp[3];
                T[0]=b0.x; T[1]=b0.y; T[2]=b0.z; T[3]=b0.w;
                T[4]=b1.x; T[5]=b1.y; T[6]=b1.z; T[7]=b1.w;
                T[8]=b2.x; T[9]=b2.y; T[10]=b2.z; T[11]=b2.w;
                T[12]=b3.x; T[13]=b3.y; T[14]=b3.z; T[15]=b3.w;

                mat4_mul(P, T, V);
                float q = 0.f;
#pragma unroll
                for (int k = 0; k < 16; ++k) {
                    float d = V[k] - MU[k];
                    q = fmaf(d * d, IS[k], q);
                }
                Ra_s[i][o] = Cc - q;
            }
            __syncthreads();

            // ======== softmax over o per row i, then scale by act ========
            for (int i = t; i < NI; i += 256) {
                float mx = -1e30f;
                for (int oo = 0; oo < 32; ++oo) mx = fmaxf(mx, Ra_s[i][oo]);
                float e[32];
                float sum = 0.f;
#pragma unroll
                for (int oo = 0; oo < 32; ++oo) {
                    e[oo] = __expf(Ra_s[i][oo] - mx);
                    sum += e[oo];
                }
                float sc = act_s[i] / sum;
#pragma unroll
                for (int oo = 0; oo < 32; ++oo) Ra_s[i][oo] = e[oo] * sc;
            }
            __syncthreads();
        }
    }
}

} // namespace

extern "C" void kernel_launch(void* const* d_in, const int* in_sizes, int n_in,
                              void* d_out, int out_size, void* d_ws, size_t ws_size,
                              hipStream_t stream) {
    const float* caps = (const float*)d_in[0];   // (8,24,24,32,17)
    const float* Tm   = (const float*)d_in[1];   // (3,3,32,32,4,4)
    const float* bu   = (const float*)d_in[2];
    const float* ba   = (const float*)d_in[3];
    float* out        = (float*)d_out;           // (8,11,11,32,17)

    dim3 grid(121, 8);
    dim3 block(256);
    hipLaunchKernelGGL(convcaps_em_kernel, grid, block, 0, stream,
                       caps, Tm, bu, ba, out);
}

// Round 2
// 171.239 us; speedup vs baseline: 1.0840x; 1.0840x over previous
//
#include <hip/hip_runtime.h>
#include <math.h>

// ConvCaps + EM routing, MI355X (gfx950).
// Shapes: caps (8,24,24,32,17) f32, trans (3,3,32,32,4,4) f32, out (8,11,11,32,17) f32.
// One 256-thread block per (b, n=oy*11+ox). Patch staged in LDS; votes recomputed
// per sweep (T slices L2-resident); mu/sigma fused via E[V^2]-mu^2.
// R2: lnp-sweep fused with next moment-sweep (softmax over o done with
// half-wave shuffle butterflies -> no Ra LDS array, 3 vote sweeps instead of 5).

namespace {

constexpr int NH   = 11;    // output spatial dim
constexpr int NI   = 288;   // 3*3*32 input capsules per position
constexpr int NO   = 32;    // output capsules
constexpr float LAM_   = 0.01f;
constexpr float EPS_   = 1e-8f;
constexpr float LOG2PI = 1.8378770664093453f;

__device__ __forceinline__ void load_PT(const float* __restrict__ pose_row,
                                        const float* __restrict__ t_row,
                                        float* P, float* T) {
    const float4* pp = reinterpret_cast<const float4*>(pose_row);
    float4 a0 = pp[0], a1 = pp[1], a2 = pp[2], a3 = pp[3];
    P[0]=a0.x; P[1]=a0.y; P[2]=a0.z; P[3]=a0.w;
    P[4]=a1.x; P[5]=a1.y; P[6]=a1.z; P[7]=a1.w;
    P[8]=a2.x; P[9]=a2.y; P[10]=a2.z; P[11]=a2.w;
    P[12]=a3.x; P[13]=a3.y; P[14]=a3.z; P[15]=a3.w;
    const float4* tp = reinterpret_cast<const float4*>(t_row);
    float4 b0 = tp[0], b1 = tp[1], b2 = tp[2], b3 = tp[3];
    T[0]=b0.x; T[1]=b0.y; T[2]=b0.z; T[3]=b0.w;
    T[4]=b1.x; T[5]=b1.y; T[6]=b1.z; T[7]=b1.w;
    T[8]=b2.x; T[9]=b2.y; T[10]=b2.z; T[11]=b2.w;
    T[12]=b3.x; T[13]=b3.y; T[14]=b3.z; T[15]=b3.w;
}

__device__ __forceinline__ void mat4_mul(const float* P, const float* T, float* V) {
#pragma unroll
    for (int p = 0; p < 4; ++p) {
#pragma unroll
        for (int r = 0; r < 4; ++r) {
            float s = P[p * 4 + 0] * T[0 * 4 + r];
            s = fmaf(P[p * 4 + 1], T[1 * 4 + r], s);
            s = fmaf(P[p * 4 + 2], T[2 * 4 + r], s);
            s = fmaf(P[p * 4 + 3], T[3 * 4 + r], s);
            V[p * 4 + r] = s;
        }
    }
}

__global__ __launch_bounds__(256, 3)
void convcaps_em_kernel(const float* __restrict__ caps,
                        const float* __restrict__ Tm,
                        const float* __restrict__ bu_p,
                        const float* __restrict__ ba_p,
                        float* __restrict__ out)
{
    // LDS: 18432 + 1152 + 16896 + 2176 + 2176 + 128 + 128 + 1024 = 42112 B -> 3 blocks/CU
    __shared__ float pose_s[NI][16];     // poses
    __shared__ float act_s[NI];          // activations
    __shared__ float red_s[4][NO][33];   // per-wave partials: m1[16], m2[16], sumR
    __shared__ float mu_s[NO][17];       // stride 17 (gcd(17,32)=1) -> conflict-free
    __shared__ float i2s_s[NO][17];      // 1/(2*sigma^2)
    __shared__ float C_s[NO];            // log(a+eps) - (L + 8*log2pi)
    __shared__ float sumR_s[NO];
    __shared__ float csum_s[NO][8];      // partials of 0.5*log(sigma^2)

    const int n  = blockIdx.x;           // 0..120
    const int b  = blockIdx.y;           // 0..7
    const int oy = n / NH;
    const int ox = n - oy * NH;
    const int t  = (int)threadIdx.x;
    const int o  = t & 31;               // output capsule (lane%32)
    const int ig = t >> 5;               // i-group 0..7
    const int wv = t >> 6;               // wave 0..3
    const int ln = t & 63;               // lane

    // ---- stage patch: 9 spatial cells x (32 caps * 17 floats) ----
    for (int idx = t; idx < 9 * 544; idx += 256) {
        int cell = idx / 544;
        int j    = idx - cell * 544;     // j = ic*17 + c
        int kx   = cell / 3;
        int ky   = cell - kx * 3;
        size_t src = ((((size_t)b * 24 + (2 * oy + kx)) * 24 + (2 * ox + ky)) * 32) * 17 + j;
        float v = caps[src];
        int ic = j / 17;
        int c  = j - ic * 17;
        int i  = cell * 32 + ic;
        if (c == 16) act_s[i] = v;
        else         pose_s[i][c] = v;
    }
    __syncthreads();

    const float beta_u = bu_p[0];
    const float beta_a = ba_p[0];
    const size_t obase = ((((size_t)b * NH + oy) * NH + ox) * NO + o) * 17;
    const int pg = ig;                   // p-group for reduction phase
    const int p0 = pg, p1 = pg + 8;

    float m1[16], m2[16], sR;

    // ================= sweep 0: ra = act/32, accumulate moments =================
#pragma unroll
    for (int k = 0; k < 16; ++k) { m1[k] = 0.f; m2[k] = 0.f; }
    sR = 0.f;
    for (int ii = 0; ii < NI / 8; ++ii) {
        const int i = ig + ii * 8;
        float ra = act_s[i] * (1.0f / 32.0f);
        float P[16], T[16], V[16];
        load_PT(&pose_s[i][0], Tm + ((size_t)i * 32 + o) * 16, P, T);
        mat4_mul(P, T, V);
#pragma unroll
        for (int k = 0; k < 16; ++k) {
            m1[k] = fmaf(ra, V[k], m1[k]);
            m2[k] = fmaf(ra * V[k], V[k], m2[k]);
        }
        sR += ra;
    }

    for (int it = 0; it < 3; ++it) {
        // ======== reduction: moments -> mu, sigma, a_out (and C for it<2) ========
#pragma unroll
        for (int k = 0; k < 16; ++k) {
            m1[k] += __shfl_xor(m1[k], 32);
            m2[k] += __shfl_xor(m2[k], 32);
        }
        sR += __shfl_xor(sR, 32);
        if (ln < 32) {
#pragma unroll
            for (int k = 0; k < 16; ++k) {
                red_s[wv][o][k]      = m1[k];
                red_s[wv][o][16 + k] = m2[k];
            }
            red_s[wv][o][32] = sR;
        }
        __syncthreads();

        float M10 = red_s[0][o][p0] + red_s[1][o][p0] + red_s[2][o][p0] + red_s[3][o][p0];
        float M20 = red_s[0][o][16+p0] + red_s[1][o][16+p0] + red_s[2][o][16+p0] + red_s[3][o][16+p0];
        float M11 = red_s[0][o][p1] + red_s[1][o][p1] + red_s[2][o][p1] + red_s[3][o][p1];
        float M21 = red_s[0][o][16+p1] + red_s[1][o][16+p1] + red_s[2][o][16+p1] + red_s[3][o][16+p1];
        if (pg == 0) {
            float S = red_s[0][o][32] + red_s[1][o][32] + red_s[2][o][32] + red_s[3][o][32];
            sumR_s[o] = S + EPS_;
        }
        __syncthreads();

        const float sumR = sumR_s[o];
        const float Sraw = sumR - EPS_;
        float mu0 = M10 / sumR;
        float sg0 = (M20 - 2.f * mu0 * M10 + mu0 * mu0 * Sraw) / sumR + EPS_;
        float mu1 = M11 / sumR;
        float sg1 = (M21 - 2.f * mu1 * M11 + mu1 * mu1 * Sraw) / sumR + EPS_;

        if (it == 2) {
            // ======== final outputs ========
            csum_s[o][pg] = 0.5f * (__logf(sg0) + __logf(sg1));
            __syncthreads();
            if (pg == 0) {
                float L = csum_s[o][0] + csum_s[o][1] + csum_s[o][2] + csum_s[o][3]
                        + csum_s[o][4] + csum_s[o][5] + csum_s[o][6] + csum_s[o][7];
                float cost = sumR * (16.f * beta_u + L);
                float a = 1.f / (1.f + __expf(-(LAM_ * (beta_a - cost))));
                out[obase + 16] = a;
            }
            out[obase + p0] = mu0;
            out[obase + p1] = mu1;
            return;
        }

        mu_s[o][p0]  = mu0;  mu_s[o][p1]  = mu1;
        i2s_s[o][p0] = 0.5f / sg0;  i2s_s[o][p1] = 0.5f / sg1;
        csum_s[o][pg] = 0.5f * (__logf(sg0) + __logf(sg1));
        __syncthreads();

        if (pg == 0) {
            float L = csum_s[o][0] + csum_s[o][1] + csum_s[o][2] + csum_s[o][3]
                    + csum_s[o][4] + csum_s[o][5] + csum_s[o][6] + csum_s[o][7];
            float cost = sumR * (16.f * beta_u + L);
            float a = 1.f / (1.f + __expf(-(LAM_ * (beta_a - cost))));
            C_s[o] = __logf(a + EPS_) - (L + 8.f * LOG2PI);
        }
        __syncthreads();

        // ======== fused sweep: lnp -> shuffle softmax over o -> R -> moments ========
        const float Cc = C_s[o];
        float MU[16], IS[16];
#pragma unroll
        for (int k = 0; k < 16; ++k) { MU[k] = mu_s[o][k]; IS[k] = i2s_s[o][k]; }

#pragma unroll
        for (int k = 0; k < 16; ++k) { m1[k] = 0.f; m2[k] = 0.f; }
        sR = 0.f;

        for (int ii = 0; ii < NI / 8; ++ii) {
            const int i = ig + ii * 8;
            float P[16], T[16], V[16];
            load_PT(&pose_s[i][0], Tm + ((size_t)i * 32 + o) * 16, P, T);
            mat4_mul(P, T, V);

            float q = 0.f;
#pragma unroll
            for (int k = 0; k < 16; ++k) {
                float d = V[k] - MU[k];
                q = fmaf(d * d, IS[k], q);
            }
            float lnp = Cc - q;     // ln_p(i,o) + log(a_out[o]+eps), one per lane(o)

            // softmax over the 32 lanes (= 32 o's) of this half-wave
            float mx = lnp;
            mx = fmaxf(mx, __shfl_xor(mx, 1));
            mx = fmaxf(mx, __shfl_xor(mx, 2));
            mx = fmaxf(mx, __shfl_xor(mx, 4));
            mx = fmaxf(mx, __shfl_xor(mx, 8));
            mx = fmaxf(mx, __shfl_xor(mx, 16));
            float e = __expf(lnp - mx);
            float sm = e;
            sm += __shfl_xor(sm, 1);
            sm += __shfl_xor(sm, 2);
            sm += __shfl_xor(sm, 4);
            sm += __shfl_xor(sm, 8);
            sm += __shfl_xor(sm, 16);
            float ra = act_s[i] * e / sm;

#pragma unroll
            for (int k = 0; k < 16; ++k) {
                m1[k] = fmaf(ra, V[k], m1[k]);
                m2[k] = fmaf(ra * V[k], V[k], m2[k]);
            }
            sR += ra;
        }
    }
}

} // namespace

extern "C" void kernel_launch(void* const* d_in, const int* in_sizes, int n_in,
                              void* d_out, int out_size, void* d_ws, size_t ws_size,
                              hipStream_t stream) {
    const float* caps = (const float*)d_in[0];   // (8,24,24,32,17)
    const float* Tm   = (const float*)d_in[1];   // (3,3,32,32,4,4)
    const float* bu   = (const float*)d_in[2];
    const float* ba   = (const float*)d_in[3];
    float* out        = (float*)d_out;           // (8,11,11,32,17)

    dim3 grid(121, 8);
    dim3 block(256);
    hipLaunchKernelGGL(convcaps_em_kernel, grid, block, 0, stream,
                       caps, Tm, bu, ba, out);
}

// Round 3
// 147.689 us; speedup vs baseline: 1.2568x; 1.1595x over previous
//
#include <hip/hip_runtime.h>
#include <math.h>

// ConvCaps + EM routing, MI355X (gfx950).
// Shapes: caps (8,24,24,32,17) f32, trans (3,3,32,32,4,4) f32, out (8,11,11,32,17) f32.
// One 256-thread block per (b, n). Patch in LDS; votes recomputed per sweep
// (T slices L2-resident); mu/sigma fused via E[V^2]-mu^2; softmax over o via
// half-wave shuffles (3 vote sweeps total).
// R3: 4 blocks/CU residency (LDS 36.7KB, VGPR<=128 via launch_bounds(256,4)) to
// kill the 2-phase dispatch tail; wave-0-only finalize (red_s[3], fewer barriers);
// fast divides; incrementing T pointer. Register indices kept compile-time via
// template<BASE> (runtime-indexed register arrays go to scratch).

namespace {

constexpr int NH   = 11;    // output spatial dim
constexpr int NI   = 288;   // 3*3*32 input capsules per position
constexpr float LAM_   = 0.01f;
constexpr float EPS_   = 1e-8f;
constexpr float LOG2PI = 1.8378770664093453f;

__device__ __forceinline__ void load_P(const float* __restrict__ pose_row, float* P) {
    const float4* pp = reinterpret_cast<const float4*>(pose_row);
    float4 a0 = pp[0], a1 = pp[1], a2 = pp[2], a3 = pp[3];
    P[0]=a0.x; P[1]=a0.y; P[2]=a0.z; P[3]=a0.w;
    P[4]=a1.x; P[5]=a1.y; P[6]=a1.z; P[7]=a1.w;
    P[8]=a2.x; P[9]=a2.y; P[10]=a2.z; P[11]=a2.w;
    P[12]=a3.x; P[13]=a3.y; P[14]=a3.z; P[15]=a3.w;
}

__device__ __forceinline__ void load_T(const float4* __restrict__ tp, float* T) {
    float4 b0 = tp[0], b1 = tp[1], b2 = tp[2], b3 = tp[3];
    T[0]=b0.x; T[1]=b0.y; T[2]=b0.z; T[3]=b0.w;
    T[4]=b1.x; T[5]=b1.y; T[6]=b1.z; T[7]=b1.w;
    T[8]=b2.x; T[9]=b2.y; T[10]=b2.z; T[11]=b2.w;
    T[12]=b3.x; T[13]=b3.y; T[14]=b3.z; T[15]=b3.w;
}

__device__ __forceinline__ void mat4_mul(const float* P, const float* T, float* V) {
#pragma unroll
    for (int p = 0; p < 4; ++p) {
#pragma unroll
        for (int r = 0; r < 4; ++r) {
            float s = P[p * 4 + 0] * T[0 * 4 + r];
            s = fmaf(P[p * 4 + 1], T[1 * 4 + r], s);
            s = fmaf(P[p * 4 + 2], T[2 * 4 + r], s);
            s = fmaf(P[p * 4 + 3], T[3 * 4 + r], s);
            V[p * 4 + r] = s;
        }
    }
}

// Finalize 8 p's with compile-time BASE so m1/m2 register indices stay static.
// Writes mu (to mu_s or out) and optionally i2s; returns sum of log(sigma^2).
template<int BASE>
__device__ __forceinline__ float finalize_half(const float* m1, const float* m2,
        const float* __restrict__ r0, const float* __restrict__ r1,
        const float* __restrict__ r2, float S, float rs, bool last,
        float* __restrict__ mu_dst, float* __restrict__ i2s_dst)
{
    float csum = 0.f;
#pragma unroll
    for (int p = 0; p < 8; ++p) {
        float M1 = m1[BASE + p] + r0[BASE + p] + r1[BASE + p] + r2[BASE + p];
        float M2 = m2[BASE + p] + r0[16 + BASE + p] + r1[16 + BASE + p] + r2[16 + BASE + p];
        float m  = M1 * rs;
        float sg = (M2 - 2.f * m * M1 + m * m * S) * rs + EPS_;
        csum += __logf(sg);
        mu_dst[BASE + p] = m;
        if (!last) i2s_dst[BASE + p] = __fdividef(0.5f, sg);
    }
    return csum;
}

__global__ __launch_bounds__(256, 4)
void convcaps_em_kernel(const float* __restrict__ caps,
                        const float* __restrict__ Tm,
                        const float* __restrict__ bu_p,
                        const float* __restrict__ ba_p,
                        float* __restrict__ out)
{
    // LDS: 18432 + 1152 + 12672 + 2176 + 2176 + 128 = 36736 B -> 4 blocks/CU
    __shared__ float pose_s[NI][16];     // poses
    __shared__ float act_s[NI];          // activations
    __shared__ float red_s[3][32][33];   // waves 1..3 partials: m1[16], m2[16], sumR
    __shared__ float mu_s[32][17];       // stride 17 -> conflict-free broadcast
    __shared__ float i2s_s[32][17];      // 1/(2*sigma^2)
    __shared__ float C_s[32];            // log(a+eps) - (L + 8*log2pi)

    const int n  = blockIdx.x;           // 0..120
    const int b  = blockIdx.y;           // 0..7
    const int oy = n / NH;
    const int ox = n - oy * NH;
    const int t  = (int)threadIdx.x;
    const int o  = t & 31;               // output capsule
    const int ig = t >> 5;               // i-group 0..7
    const int wv = t >> 6;               // wave 0..3
    const int ln = t & 63;               // lane
    const int hi = ln >> 5;              // half within wave

    // ---- stage patch: 9 spatial cells x (32 caps * 17 floats) ----
    for (int idx = t; idx < 9 * 544; idx += 256) {
        int cell = idx / 544;
        int j    = idx - cell * 544;     // j = ic*17 + c
        int kx   = cell / 3;
        int ky   = cell - kx * 3;
        size_t src = ((((size_t)b * 24 + (2 * oy + kx)) * 24 + (2 * ox + ky)) * 32) * 17 + j;
        float v = caps[src];
        int ic = j / 17;
        int c  = j - ic * 17;
        int i  = cell * 32 + ic;
        if (c == 16) act_s[i] = v;
        else         pose_s[i][c] = v;
    }
    __syncthreads();

    const float beta_u = bu_p[0];
    const float beta_a = ba_p[0];
    const size_t ob = ((((size_t)b * NH + oy) * NH + ox) * 32 + o) * 17;

    float m1[16], m2[16], sR;

    // ================= sweep 0: ra = act/32, accumulate moments =================
#pragma unroll
    for (int k = 0; k < 16; ++k) { m1[k] = 0.f; m2[k] = 0.f; }
    sR = 0.f;
    {
        const float4* tptr = reinterpret_cast<const float4*>(Tm) + ((size_t)ig * 32 + o) * 4;
        for (int ii = 0; ii < NI / 8; ++ii, tptr += 1024) {
            const int i = ig + ii * 8;
            float ra = act_s[i] * (1.0f / 32.0f);
            float P[16], T[16], V[16];
            load_P(&pose_s[i][0], P);
            load_T(tptr, T);
            mat4_mul(P, T, V);
#pragma unroll
            for (int k = 0; k < 16; ++k) {
                float rv = ra * V[k];
                m1[k] += rv;
                m2[k] = fmaf(rv, V[k], m2[k]);
            }
            sR += ra;
        }
    }

    for (int it = 0; it < 3; ++it) {
        // ---- combine ig pairs within wave ----
#pragma unroll
        for (int k = 0; k < 16; ++k) {
            m1[k] += __shfl_xor(m1[k], 32);
            m2[k] += __shfl_xor(m2[k], 32);
        }
        sR += __shfl_xor(sR, 32);
        if (wv > 0 && ln < 32) {
#pragma unroll
            for (int k = 0; k < 16; ++k) {
                red_s[wv - 1][o][k]      = m1[k];
                red_s[wv - 1][o][16 + k] = m2[k];
            }
            red_s[wv - 1][o][32] = sR;
        }
        __syncthreads();

        // ---- wave-0 finalize: mu, sigma, a (and C for it<2) ----
        if (wv == 0) {
            const bool last = (it == 2);
            const float* r0 = &red_s[0][o][0];
            const float* r1 = &red_s[1][o][0];
            const float* r2 = &red_s[2][o][0];
            float S    = sR + r0[32] + r1[32] + r2[32];
            float sumR = S + EPS_;
            float rs   = __fdividef(1.f, sumR);
            float* mu_dst  = last ? (out + ob) : &mu_s[o][0];
            float* i2s_dst = &i2s_s[o][0];
            float csum = (hi == 0)
                ? finalize_half<0>(m1, m2, r0, r1, r2, S, rs, last, mu_dst, i2s_dst)
                : finalize_half<8>(m1, m2, r0, r1, r2, S, rs, last, mu_dst, i2s_dst);
            csum *= 0.5f;
            float L = csum + __shfl_xor(csum, 32);     // after reconvergence
            float cost = sumR * (16.f * beta_u + L);
            float a = __fdividef(1.f, 1.f + __expf(-(LAM_ * (beta_a - cost))));
            if (hi == 0) {
                if (last) out[ob + 16] = a;
                else      C_s[o] = __logf(a + EPS_) - (L + 8.f * LOG2PI);
            }
        }
        if (it == 2) return;
        __syncthreads();

        // ======== fused sweep: lnp -> shuffle softmax over o -> R -> moments ========
        const float Cc = C_s[o];
        float MU[16], IS[16];
#pragma unroll
        for (int k = 0; k < 16; ++k) { MU[k] = mu_s[o][k]; IS[k] = i2s_s[o][k]; }

#pragma unroll
        for (int k = 0; k < 16; ++k) { m1[k] = 0.f; m2[k] = 0.f; }
        sR = 0.f;

        const float4* tptr = reinterpret_cast<const float4*>(Tm) + ((size_t)ig * 32 + o) * 4;
        for (int ii = 0; ii < NI / 8; ++ii, tptr += 1024) {
            const int i = ig + ii * 8;
            float P[16], T[16], V[16];
            load_P(&pose_s[i][0], P);
            load_T(tptr, T);
            mat4_mul(P, T, V);

            float q = 0.f;
#pragma unroll
            for (int k = 0; k < 16; ++k) {
                float d = V[k] - MU[k];
                q = fmaf(d * d, IS[k], q);
            }
            float lnp = Cc - q;

            // softmax over the 32 lanes (= 32 o's) of this half-wave
            float mx = lnp;
            mx = fmaxf(mx, __shfl_xor(mx, 1));
            mx = fmaxf(mx, __shfl_xor(mx, 2));
            mx = fmaxf(mx, __shfl_xor(mx, 4));
            mx = fmaxf(mx, __shfl_xor(mx, 8));
            mx = fmaxf(mx, __shfl_xor(mx, 16));
            float e = __expf(lnp - mx);
            float sm = e;
            sm += __shfl_xor(sm, 1);
            sm += __shfl_xor(sm, 2);
            sm += __shfl_xor(sm, 4);
            sm += __shfl_xor(sm, 8);
            sm += __shfl_xor(sm, 16);
            float ra = __fdividef(act_s[i] * e, sm);

#pragma unroll
            for (int k = 0; k < 16; ++k) {
                float rv = ra * V[k];
                m1[k] += rv;
                m2[k] = fmaf(rv, V[k], m2[k]);
            }
            sR += ra;
        }
    }
}

} // namespace

extern "C" void kernel_launch(void* const* d_in, const int* in_sizes, int n_in,
                              void* d_out, int out_size, void* d_ws, size_t ws_size,
                              hipStream_t stream) {
    const float* caps = (const float*)d_in[0];   // (8,24,24,32,17)
    const float* Tm   = (const float*)d_in[1];   // (3,3,32,32,4,4)
    const float* bu   = (const float*)d_in[2];
    const float* ba   = (const float*)d_in[3];
    float* out        = (float*)d_out;           // (8,11,11,32,17)

    dim3 grid(121, 8);
    dim3 block(256);
    hipLaunchKernelGGL(convcaps_em_kernel, grid, block, 0, stream,
                       caps, Tm, bu, ba, out);
}

// Round 4
// 145.649 us; speedup vs baseline: 1.2744x; 1.0140x over previous
//
#include <hip/hip_runtime.h>
#include <math.h>

// ConvCaps + EM routing, MI355X (gfx950).
// Shapes: caps (8,24,24,32,17) f32, trans (3,3,32,32,4,4) f32, out (8,11,11,32,17) f32.
// One 256-thread block per (b, n). Patch in LDS; votes recomputed per sweep
// (T slices L2-resident); mu/sigma fused via E[V^2]-mu^2; softmax over o via
// half-wave shuffles (3 vote sweeps total); 4 blocks/CU residency.
// R4: packed fp32 math — votes / moments / (V-mu)^2 loops written as
// ext_vector_type(2) so the backend emits v_pk_fma_f32 / v_pk_add_f32 /
// v_pk_mul_f32 (VOP3P): ~halves the dominant VALU instruction count.
// All register indexing stays compile-time (static unrolls + template<BASE>).

namespace {

constexpr int NH   = 11;    // output spatial dim
constexpr int NI   = 288;   // 3*3*32 input capsules per position
constexpr float LAM_   = 0.01f;
constexpr float EPS_   = 1e-8f;
constexpr float LOG2PI = 1.8378770664093453f;

typedef __attribute__((ext_vector_type(2))) float f32x2;

__device__ __forceinline__ f32x2 splat(float s) { return (f32x2){s, s}; }
__device__ __forceinline__ f32x2 vfma(f32x2 a, f32x2 b, f32x2 c) {
    return __builtin_elementwise_fma(a, b, c);
}

// votes: V2[p][h] = sum_q P[p][q] * T[q][r], r = 2h+e packed in f32x2
__device__ __forceinline__ void votes_pk(const float4* __restrict__ Prow4,
                                         const f32x2 T2[4][2], f32x2 V2[4][2]) {
    float4 pr0 = Prow4[0], pr1 = Prow4[1], pr2 = Prow4[2], pr3 = Prow4[3];
#pragma unroll
    for (int h = 0; h < 2; ++h) {
        {
            f32x2 s = splat(pr0.x) * T2[0][h];
            s = vfma(splat(pr0.y), T2[1][h], s);
            s = vfma(splat(pr0.z), T2[2][h], s);
            V2[0][h] = vfma(splat(pr0.w), T2[3][h], s);
        }
        {
            f32x2 s = splat(pr1.x) * T2[0][h];
            s = vfma(splat(pr1.y), T2[1][h], s);
            s = vfma(splat(pr1.z), T2[2][h], s);
            V2[1][h] = vfma(splat(pr1.w), T2[3][h], s);
        }
        {
            f32x2 s = splat(pr2.x) * T2[0][h];
            s = vfma(splat(pr2.y), T2[1][h], s);
            s = vfma(splat(pr2.z), T2[2][h], s);
            V2[2][h] = vfma(splat(pr2.w), T2[3][h], s);
        }
        {
            f32x2 s = splat(pr3.x) * T2[0][h];
            s = vfma(splat(pr3.y), T2[1][h], s);
            s = vfma(splat(pr3.z), T2[2][h], s);
            V2[3][h] = vfma(splat(pr3.w), T2[3][h], s);
        }
    }
}

__device__ __forceinline__ void load_T2(const float4* __restrict__ tp, f32x2 T2[4][2]) {
    float4 b0 = tp[0], b1 = tp[1], b2 = tp[2], b3 = tp[3];
    T2[0][0] = (f32x2){b0.x, b0.y};  T2[0][1] = (f32x2){b0.z, b0.w};
    T2[1][0] = (f32x2){b1.x, b1.y};  T2[1][1] = (f32x2){b1.z, b1.w};
    T2[2][0] = (f32x2){b2.x, b2.y};  T2[2][1] = (f32x2){b2.z, b2.w};
    T2[3][0] = (f32x2){b3.x, b3.y};  T2[3][1] = (f32x2){b3.z, b3.w};
}

// Finalize 8 p's with compile-time BASE so register indices stay static.
template<int BASE>
__device__ __forceinline__ float finalize_half(const f32x2* m1v, const f32x2* m2v,
        const float* __restrict__ r0, const float* __restrict__ r1,
        const float* __restrict__ r2, float S, float rs, bool last,
        float* __restrict__ mu_dst, float* __restrict__ i2s_dst)
{
    float csum = 0.f;
#pragma unroll
    for (int p = 0; p < 8; ++p) {
        constexpr int B = BASE;
        float M1 = m1v[(B + 0) / 2 + p / 2 * 0][0]; // placeholder avoided below
        (void)M1;
        // k = B + p (static): element [k/2][k&1]
        float m1k = m1v[(B + p) >> 1][(B + p) & 1];
        float m2k = m2v[(B + p) >> 1][(B + p) & 1];
        float M1f = m1k + r0[B + p] + r1[B + p] + r2[B + p];
        float M2f = m2k + r0[16 + B + p] + r1[16 + B + p] + r2[16 + B + p];
        float m  = M1f * rs;
        float sg = (M2f - 2.f * m * M1f + m * m * S) * rs + EPS_;
        csum += __logf(sg);
        mu_dst[B + p] = m;
        if (!last) i2s_dst[B + p] = __fdividef(0.5f, sg);
    }
    return csum;
}

__global__ __launch_bounds__(256, 4)
void convcaps_em_kernel(const float* __restrict__ caps,
                        const float* __restrict__ Tm,
                        const float* __restrict__ bu_p,
                        const float* __restrict__ ba_p,
                        float* __restrict__ out)
{
    // LDS: 18432 + 1152 + 12672 + 2304 + 2304 + 128 = 36992 B -> 4 blocks/CU
    __shared__ float pose_s[NI][16];     // poses
    __shared__ float act_s[NI];          // activations
    __shared__ float red_s[3][32][33];   // waves 1..3 partials: m1[16], m2[16], sumR
    __shared__ float mu_s[32][18];       // stride 18: f32x2-aligned, 2-way bank alias (free)
    __shared__ float i2s_s[32][18];      // 1/(2*sigma^2)
    __shared__ float C_s[32];            // log(a+eps) - (L + 8*log2pi)

    const int n  = blockIdx.x;           // 0..120
    const int b  = blockIdx.y;           // 0..7
    const int oy = n / NH;
    const int ox = n - oy * NH;
    const int t  = (int)threadIdx.x;
    const int o  = t & 31;               // output capsule
    const int ig = t >> 5;               // i-group 0..7
    const int wv = t >> 6;               // wave 0..3
    const int ln = t & 63;               // lane
    const int hi = ln >> 5;              // half within wave

    // ---- stage patch: 9 spatial cells x (32 caps * 17 floats) ----
    for (int idx = t; idx < 9 * 544; idx += 256) {
        int cell = idx / 544;
        int j    = idx - cell * 544;     // j = ic*17 + c
        int kx   = cell / 3;
        int ky   = cell - kx * 3;
        size_t src = ((((size_t)b * 24 + (2 * oy + kx)) * 24 + (2 * ox + ky)) * 32) * 17 + j;
        float v = caps[src];
        int ic = j / 17;
        int c  = j - ic * 17;
        int i  = cell * 32 + ic;
        if (c == 16) act_s[i] = v;
        else         pose_s[i][c] = v;
    }
    __syncthreads();

    const float beta_u = bu_p[0];
    const float beta_a = ba_p[0];
    const size_t ob = ((((size_t)b * NH + oy) * NH + ox) * 32 + o) * 17;

    f32x2 m1v[8], m2v[8];                // flat k = p*4+r, element k -> [k/2][k&1]
    float sR;

    // ================= sweep 0: ra = act/32, accumulate moments =================
#pragma unroll
    for (int j = 0; j < 8; ++j) { m1v[j] = splat(0.f); m2v[j] = splat(0.f); }
    sR = 0.f;
    {
        const float4* tptr = reinterpret_cast<const float4*>(Tm) + ((size_t)ig * 32 + o) * 4;
        for (int ii = 0; ii < NI / 8; ++ii, tptr += 1024) {
            const int i = ig + ii * 8;
            float ra = act_s[i] * (1.0f / 32.0f);
            f32x2 T2[4][2], V2[4][2];
            load_T2(tptr, T2);
            votes_pk(reinterpret_cast<const float4*>(&pose_s[i][0]), T2, V2);
            f32x2 ra2 = splat(ra);
#pragma unroll
            for (int p = 0; p < 4; ++p) {
#pragma unroll
                for (int h = 0; h < 2; ++h) {
                    f32x2 rv = ra2 * V2[p][h];
                    m1v[p * 2 + h] += rv;
                    m2v[p * 2 + h] = vfma(rv, V2[p][h], m2v[p * 2 + h]);
                }
            }
            sR += ra;
        }
    }

    for (int it = 0; it < 3; ++it) {
        // ---- combine ig pairs within wave ----
#pragma unroll
        for (int j = 0; j < 8; ++j) {
            m1v[j][0] += __shfl_xor(m1v[j][0], 32);
            m1v[j][1] += __shfl_xor(m1v[j][1], 32);
            m2v[j][0] += __shfl_xor(m2v[j][0], 32);
            m2v[j][1] += __shfl_xor(m2v[j][1], 32);
        }
        sR += __shfl_xor(sR, 32);
        if (wv > 0 && ln < 32) {
#pragma unroll
            for (int j = 0; j < 8; ++j) {
                red_s[wv - 1][o][2 * j]          = m1v[j][0];
                red_s[wv - 1][o][2 * j + 1]      = m1v[j][1];
                red_s[wv - 1][o][16 + 2 * j]     = m2v[j][0];
                red_s[wv - 1][o][16 + 2 * j + 1] = m2v[j][1];
            }
            red_s[wv - 1][o][32] = sR;
        }
        __syncthreads();

        // ---- wave-0 finalize: mu, sigma, a (and C for it<2) ----
        if (wv == 0) {
            const bool last = (it == 2);
            const float* r0 = &red_s[0][o][0];
            const float* r1 = &red_s[1][o][0];
            const float* r2 = &red_s[2][o][0];
            float S    = sR + r0[32] + r1[32] + r2[32];
            float sumR = S + EPS_;
            float rs   = __fdividef(1.f, sumR);
            float* mu_dst  = last ? (out + ob) : &mu_s[o][0];
            float* i2s_dst = &i2s_s[o][0];
            float csum = (hi == 0)
                ? finalize_half<0>(m1v, m2v, r0, r1, r2, S, rs, last, mu_dst, i2s_dst)
                : finalize_half<8>(m1v, m2v, r0, r1, r2, S, rs, last, mu_dst, i2s_dst);
            csum *= 0.5f;
            float L = csum + __shfl_xor(csum, 32);     // after reconvergence
            float cost = sumR * (16.f * beta_u + L);
            float a = __fdividef(1.f, 1.f + __expf(-(LAM_ * (beta_a - cost))));
            if (hi == 0) {
                if (last) out[ob + 16] = a;
                else      C_s[o] = __logf(a + EPS_) - (L + 8.f * LOG2PI);
            }
        }
        if (it == 2) return;
        __syncthreads();

        // ======== fused sweep: lnp -> shuffle softmax over o -> R -> moments ========
        const float Cc = C_s[o];
        f32x2 MU2[8], IS2[8];
        {
            const f32x2* mrow = reinterpret_cast<const f32x2*>(&mu_s[o][0]);
            const f32x2* irow = reinterpret_cast<const f32x2*>(&i2s_s[o][0]);
#pragma unroll
            for (int j = 0; j < 8; ++j) { MU2[j] = mrow[j]; IS2[j] = irow[j]; }
        }

#pragma unroll
        for (int j = 0; j < 8; ++j) { m1v[j] = splat(0.f); m2v[j] = splat(0.f); }
        sR = 0.f;

        const float4* tptr = reinterpret_cast<const float4*>(Tm) + ((size_t)ig * 32 + o) * 4;
        for (int ii = 0; ii < NI / 8; ++ii, tptr += 1024) {
            const int i = ig + ii * 8;
            f32x2 T2[4][2], V2[4][2];
            load_T2(tptr, T2);
            votes_pk(reinterpret_cast<const float4*>(&pose_s[i][0]), T2, V2);

            f32x2 q2 = splat(0.f);
#pragma unroll
            for (int p = 0; p < 4; ++p) {
#pragma unroll
                for (int h = 0; h < 2; ++h) {
                    f32x2 d = V2[p][h] - MU2[p * 2 + h];
                    q2 = vfma(d * d, IS2[p * 2 + h], q2);
                }
            }
            float lnp = Cc - (q2[0] + q2[1]);

            // softmax over the 32 lanes (= 32 o's) of this half-wave
            float mx = lnp;
            mx = fmaxf(mx, __shfl_xor(mx, 1));
            mx = fmaxf(mx, __shfl_xor(mx, 2));
            mx = fmaxf(mx, __shfl_xor(mx, 4));
            mx = fmaxf(mx, __shfl_xor(mx, 8));
            mx = fmaxf(mx, __shfl_xor(mx, 16));
            float e = __expf(lnp - mx);
            float sm = e;
            sm += __shfl_xor(sm, 1);
            sm += __shfl_xor(sm, 2);
            sm += __shfl_xor(sm, 4);
            sm += __shfl_xor(sm, 8);
            sm += __shfl_xor(sm, 16);
            float ra = __fdividef(act_s[i] * e, sm);

            f32x2 ra2 = splat(ra);
#pragma unroll
            for (int p = 0; p < 4; ++p) {
#pragma unroll
                for (int h = 0; h < 2; ++h) {
                    f32x2 rv = ra2 * V2[p][h];
                    m1v[p * 2 + h] += rv;
                    m2v[p * 2 + h] = vfma(rv, V2[p][h], m2v[p * 2 + h]);
                }
            }
            sR += ra;
        }
    }
}

} // namespace

extern "C" void kernel_launch(void* const* d_in, const int* in_sizes, int n_in,
                              void* d_out, int out_size, void* d_ws, size_t ws_size,
                              hipStream_t stream) {
    const float* caps = (const float*)d_in[0];   // (8,24,24,32,17)
    const float* Tm   = (const float*)d_in[1];   // (3,3,32,32,4,4)
    const float* bu   = (const float*)d_in[2];
    const float* ba   = (const float*)d_in[3];
    float* out        = (float*)d_out;           // (8,11,11,32,17)

    dim3 grid(121, 8);
    dim3 block(256);
    hipLaunchKernelGGL(convcaps_em_kernel, grid, block, 0, stream,
                       caps, Tm, bu, ba, out);
}

// Round 5
// 135.508 us; speedup vs baseline: 1.3698x; 1.0748x over previous
//
#include <hip/hip_runtime.h>
#include <math.h>

// ConvCaps + EM routing, MI355X (gfx950).
// Shapes: caps (8,24,24,32,17) f32, trans (3,3,32,32,4,4) f32, out (8,11,11,32,17) f32.
// One 256-thread block per (b, n). Patch in LDS; votes recomputed per sweep
// (T slices L2-resident); mu/sigma fused via E[V^2]-mu^2; softmax over o via
// butterfly reduction per half-wave; 4 blocks/CU; packed fp32 (v_pk_*) math.
// R5: (a) softmax butterflies via DPP (quad_perm xor1/xor2, row_half_mirror,
// row_mirror) + ONE ds_swizzle xor16 — cross-lane LDS-pipe ops per chain 10->2
// (latency-bound fix); (b) coalesced epilogue via fin_s staging (kills 4.4x
// write amplification). Register indexing stays compile-time throughout.

namespace {

constexpr int NH   = 11;    // output spatial dim
constexpr int NI   = 288;   // 3*3*32 input capsules per position
constexpr float LAM_   = 0.01f;
constexpr float EPS_   = 1e-8f;
constexpr float LOG2PI = 1.8378770664093453f;

typedef __attribute__((ext_vector_type(2))) float f32x2;

__device__ __forceinline__ f32x2 splat(float s) { return (f32x2){s, s}; }
__device__ __forceinline__ f32x2 vfma(f32x2 a, f32x2 b, f32x2 c) {
    return __builtin_elementwise_fma(a, b, c);
}

// ---- butterfly reductions over the 32 lanes of a half-wave ----
// 4 DPP steps (VALU-speed, within 16-lane rows) + 1 ds_swizzle xor16.
__device__ __forceinline__ float red32_max(float x) {
    int y;
    y = __builtin_amdgcn_update_dpp(0, __float_as_int(x), 0xB1, 0xF, 0xF, true);  // quad_perm xor1
    x = fmaxf(x, __int_as_float(y));
    y = __builtin_amdgcn_update_dpp(0, __float_as_int(x), 0x4E, 0xF, 0xF, true);  // quad_perm xor2
    x = fmaxf(x, __int_as_float(y));
    y = __builtin_amdgcn_update_dpp(0, __float_as_int(x), 0x141, 0xF, 0xF, true); // row_half_mirror
    x = fmaxf(x, __int_as_float(y));
    y = __builtin_amdgcn_update_dpp(0, __float_as_int(x), 0x140, 0xF, 0xF, true); // row_mirror
    x = fmaxf(x, __int_as_float(y));
    y = __builtin_amdgcn_ds_swizzle(__float_as_int(x), 0x401F);                   // xor16
    x = fmaxf(x, __int_as_float(y));
    return x;
}
__device__ __forceinline__ float red32_sum(float x) {
    int y;
    y = __builtin_amdgcn_update_dpp(0, __float_as_int(x), 0xB1, 0xF, 0xF, true);
    x += __int_as_float(y);
    y = __builtin_amdgcn_update_dpp(0, __float_as_int(x), 0x4E, 0xF, 0xF, true);
    x += __int_as_float(y);
    y = __builtin_amdgcn_update_dpp(0, __float_as_int(x), 0x141, 0xF, 0xF, true);
    x += __int_as_float(y);
    y = __builtin_amdgcn_update_dpp(0, __float_as_int(x), 0x140, 0xF, 0xF, true);
    x += __int_as_float(y);
    y = __builtin_amdgcn_ds_swizzle(__float_as_int(x), 0x401F);
    x += __int_as_float(y);
    return x;
}

// votes: V2[p][h] = sum_q P[p][q] * T[q][r], r = 2h+e packed in f32x2
__device__ __forceinline__ void votes_pk(const float4* __restrict__ Prow4,
                                         const f32x2 T2[4][2], f32x2 V2[4][2]) {
    float4 pr0 = Prow4[0], pr1 = Prow4[1], pr2 = Prow4[2], pr3 = Prow4[3];
#pragma unroll
    for (int h = 0; h < 2; ++h) {
        {
            f32x2 s = splat(pr0.x) * T2[0][h];
            s = vfma(splat(pr0.y), T2[1][h], s);
            s = vfma(splat(pr0.z), T2[2][h], s);
            V2[0][h] = vfma(splat(pr0.w), T2[3][h], s);
        }
        {
            f32x2 s = splat(pr1.x) * T2[0][h];
            s = vfma(splat(pr1.y), T2[1][h], s);
            s = vfma(splat(pr1.z), T2[2][h], s);
            V2[1][h] = vfma(splat(pr1.w), T2[3][h], s);
        }
        {
            f32x2 s = splat(pr2.x) * T2[0][h];
            s = vfma(splat(pr2.y), T2[1][h], s);
            s = vfma(splat(pr2.z), T2[2][h], s);
            V2[2][h] = vfma(splat(pr2.w), T2[3][h], s);
        }
        {
            f32x2 s = splat(pr3.x) * T2[0][h];
            s = vfma(splat(pr3.y), T2[1][h], s);
            s = vfma(splat(pr3.z), T2[2][h], s);
            V2[3][h] = vfma(splat(pr3.w), T2[3][h], s);
        }
    }
}

__device__ __forceinline__ void load_T2(const float4* __restrict__ tp, f32x2 T2[4][2]) {
    float4 b0 = tp[0], b1 = tp[1], b2 = tp[2], b3 = tp[3];
    T2[0][0] = (f32x2){b0.x, b0.y};  T2[0][1] = (f32x2){b0.z, b0.w};
    T2[1][0] = (f32x2){b1.x, b1.y};  T2[1][1] = (f32x2){b1.z, b1.w};
    T2[2][0] = (f32x2){b2.x, b2.y};  T2[2][1] = (f32x2){b2.z, b2.w};
    T2[3][0] = (f32x2){b3.x, b3.y};  T2[3][1] = (f32x2){b3.z, b3.w};
}

// Finalize 8 p's with compile-time BASE so register indices stay static.
template<int BASE>
__device__ __forceinline__ float finalize_half(const f32x2* m1v, const f32x2* m2v,
        const float* __restrict__ r0, const float* __restrict__ r1,
        const float* __restrict__ r2, float S, float rs, bool last,
        float* __restrict__ mu_dst, float* __restrict__ i2s_dst)
{
    float csum = 0.f;
#pragma unroll
    for (int p = 0; p < 8; ++p) {
        constexpr int B = BASE;
        float m1k = m1v[(B + p) >> 1][(B + p) & 1];
        float m2k = m2v[(B + p) >> 1][(B + p) & 1];
        float M1f = m1k + r0[B + p] + r1[B + p] + r2[B + p];
        float M2f = m2k + r0[16 + B + p] + r1[16 + B + p] + r2[16 + B + p];
        float m  = M1f * rs;
        float sg = (M2f - 2.f * m * M1f + m * m * S) * rs + EPS_;
        csum += __logf(sg);
        mu_dst[B + p] = m;
        if (!last) i2s_dst[B + p] = __fdividef(0.5f, sg);
    }
    return csum;
}

__global__ __launch_bounds__(256, 4)
void convcaps_em_kernel(const float* __restrict__ caps,
                        const float* __restrict__ Tm,
                        const float* __restrict__ bu_p,
                        const float* __restrict__ ba_p,
                        float* __restrict__ out)
{
    // LDS: 18432 + 1152 + 12672 + 2304 + 2304 + 128 + 2176 = 39168 B -> 4 blocks/CU
    __shared__ float pose_s[NI][16];     // poses
    __shared__ float act_s[NI];          // activations
    __shared__ float red_s[3][32][33];   // waves 1..3 partials: m1[16], m2[16], sumR
    __shared__ float mu_s[32][18];       // stride 18: f32x2-aligned
    __shared__ float i2s_s[32][18];      // 1/(2*sigma^2)
    __shared__ float C_s[32];            // log(a+eps) - (L + 8*log2pi)
    __shared__ float fin_s[32][17];      // final (mu,a) staging for coalesced store

    const int n  = blockIdx.x;           // 0..120
    const int b  = blockIdx.y;           // 0..7
    const int oy = n / NH;
    const int ox = n - oy * NH;
    const int t  = (int)threadIdx.x;
    const int o  = t & 31;               // output capsule
    const int ig = t >> 5;               // i-group 0..7
    const int wv = t >> 6;               // wave 0..3
    const int ln = t & 63;               // lane
    const int hi = ln >> 5;              // half within wave

    // ---- stage patch: 9 spatial cells x (32 caps * 17 floats) ----
    for (int idx = t; idx < 9 * 544; idx += 256) {
        int cell = idx / 544;
        int j    = idx - cell * 544;     // j = ic*17 + c
        int kx   = cell / 3;
        int ky   = cell - kx * 3;
        size_t src = ((((size_t)b * 24 + (2 * oy + kx)) * 24 + (2 * ox + ky)) * 32) * 17 + j;
        float v = caps[src];
        int ic = j / 17;
        int c  = j - ic * 17;
        int i  = cell * 32 + ic;
        if (c == 16) act_s[i] = v;
        else         pose_s[i][c] = v;
    }
    __syncthreads();

    const float beta_u = bu_p[0];
    const float beta_a = ba_p[0];
    const size_t oblk = ((((size_t)b * NH + oy) * NH + ox) * 32) * 17;

    f32x2 m1v[8], m2v[8];                // flat k = p*4+r, element k -> [k/2][k&1]
    float sR;

    // ================= sweep 0: ra = act/32, accumulate moments =================
#pragma unroll
    for (int j = 0; j < 8; ++j) { m1v[j] = splat(0.f); m2v[j] = splat(0.f); }
    sR = 0.f;
    {
        const float4* tptr = reinterpret_cast<const float4*>(Tm) + ((size_t)ig * 32 + o) * 4;
        for (int ii = 0; ii < NI / 8; ++ii, tptr += 1024) {
            const int i = ig + ii * 8;
            float ra = act_s[i] * (1.0f / 32.0f);
            f32x2 T2[4][2], V2[4][2];
            load_T2(tptr, T2);
            votes_pk(reinterpret_cast<const float4*>(&pose_s[i][0]), T2, V2);
            f32x2 ra2 = splat(ra);
#pragma unroll
            for (int p = 0; p < 4; ++p) {
#pragma unroll
                for (int h = 0; h < 2; ++h) {
                    f32x2 rv = ra2 * V2[p][h];
                    m1v[p * 2 + h] += rv;
                    m2v[p * 2 + h] = vfma(rv, V2[p][h], m2v[p * 2 + h]);
                }
            }
            sR += ra;
        }
    }

    for (int it = 0; it < 3; ++it) {
        // ---- combine ig pairs within wave ----
#pragma unroll
        for (int j = 0; j < 8; ++j) {
            m1v[j][0] += __shfl_xor(m1v[j][0], 32);
            m1v[j][1] += __shfl_xor(m1v[j][1], 32);
            m2v[j][0] += __shfl_xor(m2v[j][0], 32);
            m2v[j][1] += __shfl_xor(m2v[j][1], 32);
        }
        sR += __shfl_xor(sR, 32);
        if (wv > 0 && ln < 32) {
#pragma unroll
            for (int j = 0; j < 8; ++j) {
                red_s[wv - 1][o][2 * j]          = m1v[j][0];
                red_s[wv - 1][o][2 * j + 1]      = m1v[j][1];
                red_s[wv - 1][o][16 + 2 * j]     = m2v[j][0];
                red_s[wv - 1][o][16 + 2 * j + 1] = m2v[j][1];
            }
            red_s[wv - 1][o][32] = sR;
        }
        __syncthreads();

        // ---- wave-0 finalize: mu, sigma, a (and C for it<2) ----
        if (wv == 0) {
            const bool last = (it == 2);
            const float* r0 = &red_s[0][o][0];
            const float* r1 = &red_s[1][o][0];
            const float* r2 = &red_s[2][o][0];
            float S    = sR + r0[32] + r1[32] + r2[32];
            float sumR = S + EPS_;
            float rs   = __fdividef(1.f, sumR);
            float* mu_dst  = last ? &fin_s[o][0] : &mu_s[o][0];
            float* i2s_dst = &i2s_s[o][0];
            float csum = (hi == 0)
                ? finalize_half<0>(m1v, m2v, r0, r1, r2, S, rs, last, mu_dst, i2s_dst)
                : finalize_half<8>(m1v, m2v, r0, r1, r2, S, rs, last, mu_dst, i2s_dst);
            csum *= 0.5f;
            float L = csum + __shfl_xor(csum, 32);     // after reconvergence
            float cost = sumR * (16.f * beta_u + L);
            float a = __fdividef(1.f, 1.f + __expf(-(LAM_ * (beta_a - cost))));
            if (hi == 0) {
                if (last) fin_s[o][16] = a;
                else      C_s[o] = __logf(a + EPS_) - (L + 8.f * LOG2PI);
            }
        }
        if (it == 2) break;
        __syncthreads();

        // ======== fused sweep: lnp -> butterfly softmax over o -> R -> moments ========
        const float Cc = C_s[o];
        f32x2 MU2[8], IS2[8];
        {
            const f32x2* mrow = reinterpret_cast<const f32x2*>(&mu_s[o][0]);
            const f32x2* irow = reinterpret_cast<const f32x2*>(&i2s_s[o][0]);
#pragma unroll
            for (int j = 0; j < 8; ++j) { MU2[j] = mrow[j]; IS2[j] = irow[j]; }
        }

#pragma unroll
        for (int j = 0; j < 8; ++j) { m1v[j] = splat(0.f); m2v[j] = splat(0.f); }
        sR = 0.f;

        const float4* tptr = reinterpret_cast<const float4*>(Tm) + ((size_t)ig * 32 + o) * 4;
        for (int ii = 0; ii < NI / 8; ++ii, tptr += 1024) {
            const int i = ig + ii * 8;
            f32x2 T2[4][2], V2[4][2];
            load_T2(tptr, T2);
            votes_pk(reinterpret_cast<const float4*>(&pose_s[i][0]), T2, V2);

            f32x2 q2 = splat(0.f);
#pragma unroll
            for (int p = 0; p < 4; ++p) {
#pragma unroll
                for (int h = 0; h < 2; ++h) {
                    f32x2 d = V2[p][h] - MU2[p * 2 + h];
                    q2 = vfma(d * d, IS2[p * 2 + h], q2);
                }
            }
            float lnp = Cc - (q2[0] + q2[1]);

            // softmax over the 32 o's of this half-wave (DPP butterfly)
            float mx = red32_max(lnp);
            float e  = __expf(lnp - mx);
            float sm = red32_sum(e);
            float ra = __fdividef(act_s[i] * e, sm);

            f32x2 ra2 = splat(ra);
#pragma unroll
            for (int p = 0; p < 4; ++p) {
#pragma unroll
                for (int h = 0; h < 2; ++h) {
                    f32x2 rv = ra2 * V2[p][h];
                    m1v[p * 2 + h] += rv;
                    m2v[p * 2 + h] = vfma(rv, V2[p][h], m2v[p * 2 + h]);
                }
            }
            sR += ra;
        }
    }

    // ---- coalesced epilogue: fin_s (32x17, packed) -> out ----
    __syncthreads();
    for (int k = t; k < 544; k += 256) {
        out[oblk + k] = (&fin_s[0][0])[k];
    }
}

} // namespace

extern "C" void kernel_launch(void* const* d_in, const int* in_sizes, int n_in,
                              void* d_out, int out_size, void* d_ws, size_t ws_size,
                              hipStream_t stream) {
    const float* caps = (const float*)d_in[0];   // (8,24,24,32,17)
    const float* Tm   = (const float*)d_in[1];   // (3,3,32,32,4,4)
    const float* bu   = (const float*)d_in[2];
    const float* ba   = (const float*)d_in[3];
    float* out        = (float*)d_out;           // (8,11,11,32,17)

    dim3 grid(121, 8);
    dim3 block(256);
    hipLaunchKernelGGL(convcaps_em_kernel, grid, block, 0, stream,
                       caps, Tm, bu, ba, out);
}